// Round 7
// baseline (280.473 us; speedup 1.0000x reference)
//
#include <hip/hip_runtime.h>
#include <hip/hip_bf16.h>

// GNNBlock: 3-layer DenseGAT, B=512 graphs x N=128 nodes, HEADS=4, HID=64.
// adj all-ones. One 1024-thread block per graph. KEY CHANGE vs r6: Xs and Ht
// share ONE 64KB LDS buffer (read-all-then-write-all per phase, 4 barriers
// per layer) -> 70KB LDS -> 2 blocks/CU -> 32 waves/CU for latency hiding.
// bf16 MFMA for X@W (+fused s/d tile on waves 12-15) and P@V (P on the fly,
// denominator in-register). __launch_bounds__(1024,8) pins VGPR<=64.

typedef unsigned short u16;
typedef __attribute__((ext_vector_type(8))) short short8;
typedef __attribute__((ext_vector_type(4))) float f32x4;

#define L2E 1.44269504088896340736f

__device__ __forceinline__ u16 f2bf(float f) {
  unsigned int u = __float_as_uint(f);
  u += 0x7fffu + ((u >> 16) & 1u);   // RNE
  return (u16)(u >> 16);
}
__device__ __forceinline__ unsigned int pk2(float a, float b) {
  __hip_bfloat162 h2 = __float22bfloat162_rn(make_float2(a, b));
  unsigned int u;
  __builtin_memcpy(&u, &h2, 4);
  return u;
}

// Shared-buffer byte offsets with XOR swizzle (G4).
// Xs view: [128 rows][256 bf16] stride 512B. Ht view: [256 rows][128 bf16] stride 256B.
__device__ __forceinline__ int xs_byte(int row, int col) {
  return (row << 9) + ((col << 1) ^ ((row & 7) << 4));
}
__device__ __forceinline__ int ht_byte(int row, int col) {
  return (row << 8) + ((col << 1) ^ ((row & 7) << 4));
}

// d_ws (bf16 elems): per layer, 17 N-tiles (16 weight + 1 wsd) of fragment
// data: elem = base + ((t*NKB + kb)*64 + lane)*8 + e.
//   L0: base 0      NKB=4  -> 34816 elems
//   L1: base 34816  NKB=8  -> 69632
//   L2: base 104448 NKB=8  -> 69632   total 174080 elems = 348160 B
__global__ void prep_w(const float* __restrict__ W0, const float* __restrict__ W1,
                       const float* __restrict__ W2,
                       const float* __restrict__ as0, const float* __restrict__ ad0,
                       const float* __restrict__ as1, const float* __restrict__ ad1,
                       const float* __restrict__ as2, const float* __restrict__ ad2,
                       u16* __restrict__ wt) {
  const int bid = blockIdx.x, tid = threadIdx.x;
  if (bid < 80) {
    // ---- part 1: W -> fragments. Block = 8 consecutive k-rows (kb,ko). ----
    const float* W; int NKB, base, rel;
    if (bid < 16)      { W = W0; NKB = 4; base = 0;      rel = bid; }
    else if (bid < 48) { W = W1; NKB = 8; base = 34816;  rel = bid - 16; }
    else               { W = W2; NKB = 8; base = 104448; rel = bid - 48; }
    const int kb = rel >> 2, ko = rel & 3;
    const int n = tid;
    union { u16 v[8]; short8 s; } u;
    #pragma unroll
    for (int e = 0; e < 8; ++e)
      u.v[e] = f2bf(W[(kb * 32 + ko * 8 + e) * 256 + n]);   // coalesced rows
    const int t = n >> 4, l15 = n & 15;
    *(short8*)(wt + base + (((t * NKB + kb) * 64 + l15 + (ko << 4)) << 3)) = u.s;
  } else if (bid < 100) {
    // ---- part 2: wsd = [W·att_src | W·att_dst | 0] tile (t=16). ----
    int b2 = bid - 80;
    const float* W; const float* as; const float* ad; int NKB, base, kb;
    if (b2 < 4)       { W = W0; as = as0; ad = ad0; NKB = 4; base = 0;      kb = b2; }
    else if (b2 < 12) { W = W1; as = as1; ad = ad1; NKB = 8; base = 34816;  kb = b2 - 4; }
    else              { W = W2; as = as2; ad = ad2; NKB = 8; base = 104448; kb = b2 - 12; }
    const int kloc = tid >> 3, col = tid & 7, h = col & 3;
    const int k = kb * 32 + kloc;
    const float* av = (col < 4) ? as : ad;
    float acc = 0.f;
    #pragma unroll 8
    for (int c = 0; c < 64; ++c)
      acc = fmaf(W[k * 256 + h * 64 + c], av[h * 64 + c], acc);
    const int lane2 = col + ((kloc >> 3) << 4), e = kloc & 7;
    const int tb = base + ((16 * NKB + kb) << 9);
    wt[tb + ((lane2) << 3) + e]     = f2bf(acc);
    wt[tb + ((lane2 + 8) << 3) + e] = 0;        // zero columns 8..15
  }
}

__global__ __launch_bounds__(1024, 8) void gat_all(
    const float* __restrict__ x, const u16* __restrict__ wt,
    const float* __restrict__ bb0, const float* __restrict__ bb1,
    const float* __restrict__ bb2, float* __restrict__ out)
{
  constexpr int AB = 0;               // 64KB shared activation buffer (Xs <-> Ht)
  constexpr int SB = 65536;           // s[4][128]*L2E f32
  constexpr int DB = 67584;           // d[4][128]*L2E f32
  constexpr int PM = 69632;           // per-wave s-max [4][4] f32 (scaled)
  constexpr int BS = 69696;           // bias [256] f32
  constexpr int OA = 70720;           // out accum [256] f32
  __shared__ __align__(16) unsigned char smem[71744];

  float* sbuf  = (float*)(smem + SB);
  float* dbuf  = (float*)(smem + DB);
  float* pmaxw = (float*)(smem + PM);
  float* bsb   = (float*)(smem + BS);
  float* oac   = (float*)(smem + OA);

  const int b    = blockIdx.x;
  const int tid  = threadIdx.x;
  const int w    = tid >> 6;          // 16 waves
  const int lane = tid & 63;
  const int l15  = lane & 15;
  const int lg   = lane >> 4;

  // ---- load X_b (128x128 f32) -> bf16 into AB (Xs layout) ----
  {
    const float4* xg = (const float4*)(x + (size_t)b * (128 * 128));
    #pragma unroll
    for (int it = 0; it < 4; ++it) {
      int e = tid + it * 1024;        // 4096 float4 total
      float4 v = xg[e];
      int row = e >> 5, c = (e & 31) << 2;
      uint2 u = { pk2(v.x, v.y), pk2(v.z, v.w) };
      *(uint2*)(smem + AB + xs_byte(row, c)) = u;
    }
  }
  __syncthreads();

  const u16* wfl[3]    = {wt, wt + 34816, wt + 104448};
  const float* bias[3] = {bb0, bb1, bb2};

  #pragma unroll
  for (int l = 0; l < 3; ++l) {
    const int NKB = (l == 0) ? 4 : 8;       // K/32
    const u16* wf = wfl[l];

    if (tid < 256) {
      bsb[tid] = bias[l][tid];
      if (l == 2) oac[tid] = 0.f;
    }

    // ---- A-read: GEMM H = X @ W, X from AB (Xs view), acc stays in regs ----
    const int mw = w & 1, nw = w >> 1;      // 2(M) x 8(N) waves, 64x32 tiles
    f32x4 acc[4][2] = {};
    for (int ks = 0; ks < NKB; ++ks) {
      const int kcol = ks * 32 + lg * 8;
      short8 afr[4];
      #pragma unroll
      for (int mi = 0; mi < 4; ++mi)
        afr[mi] = *(const short8*)(smem + AB + xs_byte(mw * 64 + mi * 16 + l15, kcol));
      short8 bfr[2];
      #pragma unroll
      for (int ni = 0; ni < 2; ++ni) {
        int t = nw * 2 + ni;
        bfr[ni] = *(const short8*)(wf + (((t * NKB + ks) * 64 + lane) << 3));
      }
      #pragma unroll
      for (int mi = 0; mi < 4; ++mi)
        #pragma unroll
        for (int ni = 0; ni < 2; ++ni)
          acc[mi][ni] = __builtin_amdgcn_mfma_f32_16x16x32_bf16(
              afr[mi], bfr[ni], acc[mi][ni], 0, 0, 0);
    }

    // ---- A': fused s/d tile (t=16) spread over waves 12..15 ----
    if (w >= 12) {
      const int mw2 = w & 1, mih = (w >> 1) & 1;   // node half, mi half
      f32x4 acc2[2] = {};
      for (int ks = 0; ks < NKB; ++ks) {
        const int kcol = ks * 32 + lg * 8;
        short8 bsd = *(const short8*)(wf + (((16 * NKB + ks) * 64 + lane) << 3));
        #pragma unroll
        for (int mi2 = 0; mi2 < 2; ++mi2) {
          short8 a = *(const short8*)(smem + AB +
              xs_byte(mw2 * 64 + (mih * 2 + mi2) * 16 + l15, kcol));
          acc2[mi2] = __builtin_amdgcn_mfma_f32_16x16x32_bf16(a, bsd, acc2[mi2], 0, 0, 0);
        }
      }
      // scale by L2E; D col=l15: 0-3 s-heads, 4-7 d-heads; row=node j.
      float mx = -3.4e38f;
      #pragma unroll
      for (int mi2 = 0; mi2 < 2; ++mi2) {
        f32x4 v = acc2[mi2] * L2E;
        if (l15 < 8) {
          float* basep = (float*)(smem + (l15 < 4 ? SB : DB))
                       + (l15 & 3) * 128 + mw2 * 64 + (mih * 2 + mi2) * 16 + lg * 4;
          *(float4*)basep = (float4){v[0], v[1], v[2], v[3]};
        }
        mx = fmaxf(mx, fmaxf(fmaxf(v[0], v[1]), fmaxf(v[2], v[3])));
      }
      mx = fmaxf(mx, __shfl_xor(mx, 16));
      mx = fmaxf(mx, __shfl_xor(mx, 32));
      if (lane < 4) pmaxw[lane * 4 + (w - 12)] = mx;  // scaled s-max partials
    }
    __syncthreads();                        // all Xs reads complete

    // ---- A-write: acc -> AB (Ht view). row=node j (lg*4+reg), col=feat (l15).
    #pragma unroll
    for (int mi = 0; mi < 4; ++mi) {
      int j0 = mw * 64 + mi * 16 + lg * 4;
      #pragma unroll
      for (int ni = 0; ni < 2; ++ni) {
        int c = nw * 32 + ni * 16 + l15;
        uint2 u = { pk2(acc[mi][ni][0], acc[mi][ni][1]),
                    pk2(acc[mi][ni][2], acc[mi][ni][3]) };
        *(uint2*)(smem + AB + ht_byte(c, j0)) = u;
      }
    }
    __syncthreads();                        // Ht ready

    // ---- F-read: PV out^T = H_head^T @ P^T; den accumulated in-register ----
    {
      const int hw = w >> 2, q = w & 3;
      f32x4 facc[4][2] = {};
      float den[2] = {0.f, 0.f};
      float dvv[2], nml[2];
      const float smax = fmaxf(fmaxf(pmaxw[hw * 4], pmaxw[hw * 4 + 1]),
                               fmaxf(pmaxw[hw * 4 + 2], pmaxw[hw * 4 + 3]));
      #pragma unroll
      for (int ni = 0; ni < 2; ++ni) {
        int i = q * 32 + ni * 16 + l15;
        dvv[ni] = dbuf[hw * 128 + i];           // scaled d_i
        float tm = smax + dvv[ni];
        nml[ni] = -fmaxf(tm, 0.2f * tm);        // -ml (scaled, post-LR)
      }
      #pragma unroll
      for (int ks = 0; ks < 4; ++ks) {
        const int j0 = ks * 32 + lg * 8;
        float4 s03 = *(const float4*)(sbuf + hw * 128 + j0);
        float4 s47 = *(const float4*)(sbuf + hw * 128 + j0 + 4);
        float sj[8] = {s03.x, s03.y, s03.z, s03.w, s47.x, s47.y, s47.z, s47.w};
        short8 afr[4];
        #pragma unroll
        for (int mi = 0; mi < 4; ++mi)
          afr[mi] = *(const short8*)(smem + AB + ht_byte(hw * 64 + mi * 16 + l15, j0));
        short8 bfr[2];
        #pragma unroll
        for (int ni = 0; ni < 2; ++ni) {
          float e[8];
          #pragma unroll
          for (int jj = 0; jj < 8; ++jj) {
            float t = sj[jj] + dvv[ni];
            t = fmaxf(t, 0.2f * t);
            e[jj] = exp2f(t + nml[ni]);
          }
          den[ni] += ((e[0] + e[1]) + (e[2] + e[3])) + ((e[4] + e[5]) + (e[6] + e[7]));
          union { short8 s; unsigned int u[4]; } pk;
          #pragma unroll
          for (int t2 = 0; t2 < 4; ++t2) pk.u[t2] = pk2(e[2 * t2], e[2 * t2 + 1]);
          bfr[ni] = pk.s;
        }
        #pragma unroll
        for (int mi = 0; mi < 4; ++mi)
          #pragma unroll
          for (int ni = 0; ni < 2; ++ni)
            facc[mi][ni] = __builtin_amdgcn_mfma_f32_16x16x32_bf16(
                afr[mi], bfr[ni], facc[mi][ni], 0, 0, 0);
      }
      float rvv[2];
      #pragma unroll
      for (int ni = 0; ni < 2; ++ni) {
        float d2 = den[ni];
        d2 += __shfl_xor(d2, 16);
        d2 += __shfl_xor(d2, 32);
        rvv[ni] = 1.f / d2;
      }
      __syncthreads();                      // all Ht reads complete

      // ---- F-write: next Xs into AB (l<2) or final reduction (l==2) ----
      if (l < 2) {
        // D: row=feature c, col=node i. out = r_i*facc + bias -> next Xs.
        #pragma unroll
        for (int mi = 0; mi < 4; ++mi) {
          int c0 = hw * 64 + mi * 16 + lg * 4;
          float b0v = bsb[c0], b1v = bsb[c0 + 1], b2v = bsb[c0 + 2], b3v = bsb[c0 + 3];
          #pragma unroll
          for (int ni = 0; ni < 2; ++ni) {
            int i = q * 32 + ni * 16 + l15;
            float r = rvv[ni];
            uint2 u = { pk2(fmaf(facc[mi][ni][0], r, b0v), fmaf(facc[mi][ni][1], r, b1v)),
                        pk2(fmaf(facc[mi][ni][2], r, b2v), fmaf(facc[mi][ni][3], r, b3v)) };
            *(uint2*)(smem + AB + xs_byte(i, c0)) = u;
          }
        }
      } else {
        // final layer: sum over nodes i (ni-sum, shfl over l15, atomic over q)
        #pragma unroll
        for (int mi = 0; mi < 4; ++mi) {
          #pragma unroll
          for (int reg = 0; reg < 4; ++reg) {
            float pv2 = facc[mi][0][reg] * rvv[0] + facc[mi][1][reg] * rvv[1];
            pv2 += __shfl_xor(pv2, 1);
            pv2 += __shfl_xor(pv2, 2);
            pv2 += __shfl_xor(pv2, 4);
            pv2 += __shfl_xor(pv2, 8);
            if (l15 == 0)
              atomicAdd(&oac[hw * 64 + mi * 16 + lg * 4 + reg], pv2);
          }
        }
      }
    }
    __syncthreads();                        // next Xs / oac ready
  }

  // bias summed over 128 nodes = 128*b[c]
  if (tid < 256) out[(size_t)b * 256 + tid] = oac[tid] + 128.f * bsb[tid];
}

extern "C" void kernel_launch(void* const* d_in, const int* in_sizes, int n_in,
                              void* d_out, int out_size, void* d_ws, size_t ws_size,
                              hipStream_t stream) {
  const float* x   = (const float*)d_in[0];
  // d_in[1] = batch_mask (unused: uniform graph layout)
  const float* W0  = (const float*)d_in[2];
  const float* as0 = (const float*)d_in[3];
  const float* ad0 = (const float*)d_in[4];
  const float* b0  = (const float*)d_in[5];
  const float* W1  = (const float*)d_in[6];
  const float* as1 = (const float*)d_in[7];
  const float* ad1 = (const float*)d_in[8];
  const float* b1  = (const float*)d_in[9];
  const float* W2  = (const float*)d_in[10];
  const float* as2 = (const float*)d_in[11];
  const float* ad2 = (const float*)d_in[12];
  const float* b2  = (const float*)d_in[13];
  u16* wt = (u16*)d_ws;                      // 348,160 bytes used

  hipLaunchKernelGGL(prep_w, dim3(100), dim3(256), 0, stream,
                     W0, W1, W2, as0, ad0, as1, ad1, as2, ad2, wt);
  hipLaunchKernelGGL(gat_all, dim3(512), dim3(1024), 0, stream,
                     x, wt, b0, b1, b2, (float*)d_out);
}

// Round 9
// 183.081 us; speedup vs baseline: 1.5320x; 1.5320x over previous
//
#include <hip/hip_runtime.h>
#include <hip/hip_bf16.h>

// GNNBlock: 3-layer DenseGAT, B=512 graphs x N=128 nodes, HEADS=4, HID=64.
// adj all-ones. One 1024-thread block per graph. Xs and Ht share ONE 64KB
// LDS buffer (read-all-then-write-all per phase, 4 barriers/layer) -> 72KB
// LDS -> 2 blocks/CU co-resident. bf16 MFMA for X@W (+fused s/d tile on
// waves 12-15) and P@V (P on the fly, denominator in-register).
// launch_bounds(1024,4): r7's (1024,8) capped VGPR at 32 -> scratch spill
// (600MB/dispatch HBM traffic, 195us). 64 VGPR already allows 8 waves/SIMD.

typedef unsigned short u16;
typedef __attribute__((ext_vector_type(8))) short short8;
typedef __attribute__((ext_vector_type(4))) float f32x4;

#define L2E 1.44269504088896340736f

__device__ __forceinline__ u16 f2bf(float f) {
  unsigned int u = __float_as_uint(f);
  u += 0x7fffu + ((u >> 16) & 1u);   // RNE
  return (u16)(u >> 16);
}
__device__ __forceinline__ unsigned int pk2(float a, float b) {
  __hip_bfloat162 h2 = __float22bfloat162_rn(make_float2(a, b));
  unsigned int u;
  __builtin_memcpy(&u, &h2, 4);
  return u;
}

// Shared-buffer byte offsets with XOR swizzle (G4).
// Xs view: [128 rows][256 bf16] stride 512B. Ht view: [256 rows][128 bf16] stride 256B.
__device__ __forceinline__ int xs_byte(int row, int col) {
  return (row << 9) + ((col << 1) ^ ((row & 7) << 4));
}
__device__ __forceinline__ int ht_byte(int row, int col) {
  return (row << 8) + ((col << 1) ^ ((row & 7) << 4));
}

// d_ws (bf16 elems): per layer, 17 N-tiles (16 weight + 1 wsd) of fragment
// data: elem = base + ((t*NKB + kb)*64 + lane)*8 + e.
//   L0: base 0      NKB=4  -> 34816 elems
//   L1: base 34816  NKB=8  -> 69632
//   L2: base 104448 NKB=8  -> 69632   total 174080 elems = 348160 B
__global__ void prep_w(const float* __restrict__ W0, const float* __restrict__ W1,
                       const float* __restrict__ W2,
                       const float* __restrict__ as0, const float* __restrict__ ad0,
                       const float* __restrict__ as1, const float* __restrict__ ad1,
                       const float* __restrict__ as2, const float* __restrict__ ad2,
                       u16* __restrict__ wt) {
  const int bid = blockIdx.x, tid = threadIdx.x;
  if (bid < 80) {
    // ---- part 1: W -> fragments. Block = 8 consecutive k-rows (kb,ko). ----
    const float* W; int NKB, base, rel;
    if (bid < 16)      { W = W0; NKB = 4; base = 0;      rel = bid; }
    else if (bid < 48) { W = W1; NKB = 8; base = 34816;  rel = bid - 16; }
    else               { W = W2; NKB = 8; base = 104448; rel = bid - 48; }
    const int kb = rel >> 2, ko = rel & 3;
    const int n = tid;
    union { u16 v[8]; short8 s; } u;
    #pragma unroll
    for (int e = 0; e < 8; ++e)
      u.v[e] = f2bf(W[(kb * 32 + ko * 8 + e) * 256 + n]);   // coalesced rows
    const int t = n >> 4, l15 = n & 15;
    *(short8*)(wt + base + (((t * NKB + kb) * 64 + l15 + (ko << 4)) << 3)) = u.s;
  } else if (bid < 100) {
    // ---- part 2: wsd = [W·att_src | W·att_dst | 0] tile (t=16). ----
    int b2 = bid - 80;
    const float* W; const float* as; const float* ad; int NKB, base, kb;
    if (b2 < 4)       { W = W0; as = as0; ad = ad0; NKB = 4; base = 0;      kb = b2; }
    else if (b2 < 12) { W = W1; as = as1; ad = ad1; NKB = 8; base = 34816;  kb = b2 - 4; }
    else              { W = W2; as = as2; ad = ad2; NKB = 8; base = 104448; kb = b2 - 12; }
    const int kloc = tid >> 3, col = tid & 7, h = col & 3;
    const int k = kb * 32 + kloc;
    const float* av = (col < 4) ? as : ad;
    float acc = 0.f;
    #pragma unroll 8
    for (int c = 0; c < 64; ++c)
      acc = fmaf(W[k * 256 + h * 64 + c], av[h * 64 + c], acc);
    const int lane2 = col + ((kloc >> 3) << 4), e = kloc & 7;
    const int tb = base + ((16 * NKB + kb) << 9);
    wt[tb + ((lane2) << 3) + e]     = f2bf(acc);
    wt[tb + ((lane2 + 8) << 3) + e] = 0;        // zero columns 8..15
  }
}

__global__ __launch_bounds__(1024, 4) void gat_all(
    const float* __restrict__ x, const u16* __restrict__ wt,
    const float* __restrict__ bb0, const float* __restrict__ bb1,
    const float* __restrict__ bb2, float* __restrict__ out)
{
  constexpr int AB = 0;               // 64KB shared activation buffer (Xs <-> Ht)
  constexpr int SB = 65536;           // s[4][128]*L2E f32
  constexpr int DB = 67584;           // d[4][128]*L2E f32
  constexpr int PM = 69632;           // per-wave s-max [4][4] f32 (scaled)
  constexpr int BS = 69696;           // bias [256] f32
  constexpr int OA = 70720;           // out accum [256] f32
  __shared__ __align__(16) unsigned char smem[71744];

  float* sbuf  = (float*)(smem + SB);
  float* dbuf  = (float*)(smem + DB);
  float* pmaxw = (float*)(smem + PM);
  float* bsb   = (float*)(smem + BS);
  float* oac   = (float*)(smem + OA);

  const int b    = blockIdx.x;
  const int tid  = threadIdx.x;
  const int w    = tid >> 6;          // 16 waves
  const int lane = tid & 63;
  const int l15  = lane & 15;
  const int lg   = lane >> 4;

  // ---- load X_b (128x128 f32) -> bf16 into AB (Xs layout) ----
  {
    const float4* xg = (const float4*)(x + (size_t)b * (128 * 128));
    #pragma unroll
    for (int it = 0; it < 4; ++it) {
      int e = tid + it * 1024;        // 4096 float4 total
      float4 v = xg[e];
      int row = e >> 5, c = (e & 31) << 2;
      uint2 u = { pk2(v.x, v.y), pk2(v.z, v.w) };
      *(uint2*)(smem + AB + xs_byte(row, c)) = u;
    }
  }
  __syncthreads();

  const u16* wfl[3]    = {wt, wt + 34816, wt + 104448};
  const float* bias[3] = {bb0, bb1, bb2};

  #pragma unroll
  for (int l = 0; l < 3; ++l) {
    const int NKB = (l == 0) ? 4 : 8;       // K/32
    const u16* wf = wfl[l];

    if (tid < 256) {
      bsb[tid] = bias[l][tid];
      if (l == 2) oac[tid] = 0.f;
    }

    // ---- A-read: GEMM H = X @ W, X from AB (Xs view), acc stays in regs ----
    const int mw = w & 1, nw = w >> 1;      // 2(M) x 8(N) waves, 64x32 tiles
    f32x4 acc[4][2] = {};
    for (int ks = 0; ks < NKB; ++ks) {
      const int kcol = ks * 32 + lg * 8;
      short8 afr[4];
      #pragma unroll
      for (int mi = 0; mi < 4; ++mi)
        afr[mi] = *(const short8*)(smem + AB + xs_byte(mw * 64 + mi * 16 + l15, kcol));
      short8 bfr[2];
      #pragma unroll
      for (int ni = 0; ni < 2; ++ni) {
        int t = nw * 2 + ni;
        bfr[ni] = *(const short8*)(wf + (((t * NKB + ks) * 64 + lane) << 3));
      }
      #pragma unroll
      for (int mi = 0; mi < 4; ++mi)
        #pragma unroll
        for (int ni = 0; ni < 2; ++ni)
          acc[mi][ni] = __builtin_amdgcn_mfma_f32_16x16x32_bf16(
              afr[mi], bfr[ni], acc[mi][ni], 0, 0, 0);
    }

    // ---- A': fused s/d tile (t=16) spread over waves 12..15 ----
    if (w >= 12) {
      const int mw2 = w & 1, mih = (w >> 1) & 1;   // node half, mi half
      f32x4 acc2[2] = {};
      for (int ks = 0; ks < NKB; ++ks) {
        const int kcol = ks * 32 + lg * 8;
        short8 bsd = *(const short8*)(wf + (((16 * NKB + ks) * 64 + lane) << 3));
        #pragma unroll
        for (int mi2 = 0; mi2 < 2; ++mi2) {
          short8 a = *(const short8*)(smem + AB +
              xs_byte(mw2 * 64 + (mih * 2 + mi2) * 16 + l15, kcol));
          acc2[mi2] = __builtin_amdgcn_mfma_f32_16x16x32_bf16(a, bsd, acc2[mi2], 0, 0, 0);
        }
      }
      // scale by L2E; D col=l15: 0-3 s-heads, 4-7 d-heads; row=node j.
      float mx = -3.4e38f;
      #pragma unroll
      for (int mi2 = 0; mi2 < 2; ++mi2) {
        f32x4 v = acc2[mi2] * L2E;
        if (l15 < 8) {
          float* basep = (float*)(smem + (l15 < 4 ? SB : DB))
                       + (l15 & 3) * 128 + mw2 * 64 + (mih * 2 + mi2) * 16 + lg * 4;
          *(float4*)basep = (float4){v[0], v[1], v[2], v[3]};
        }
        mx = fmaxf(mx, fmaxf(fmaxf(v[0], v[1]), fmaxf(v[2], v[3])));
      }
      mx = fmaxf(mx, __shfl_xor(mx, 16));
      mx = fmaxf(mx, __shfl_xor(mx, 32));
      if (lane < 4) pmaxw[lane * 4 + (w - 12)] = mx;  // scaled s-max partials
    }
    __syncthreads();                        // all Xs reads complete

    // ---- A-write: acc -> AB (Ht view). row=node j (lg*4+reg), col=feat (l15).
    #pragma unroll
    for (int mi = 0; mi < 4; ++mi) {
      int j0 = mw * 64 + mi * 16 + lg * 4;
      #pragma unroll
      for (int ni = 0; ni < 2; ++ni) {
        int c = nw * 32 + ni * 16 + l15;
        uint2 u = { pk2(acc[mi][ni][0], acc[mi][ni][1]),
                    pk2(acc[mi][ni][2], acc[mi][ni][3]) };
        *(uint2*)(smem + AB + ht_byte(c, j0)) = u;
      }
    }
    __syncthreads();                        // Ht ready

    // ---- F-read: PV out^T = H_head^T @ P^T; den accumulated in-register ----
    {
      const int hw = w >> 2, q = w & 3;
      f32x4 facc[4][2] = {};
      float den[2] = {0.f, 0.f};
      float dvv[2], nml[2];
      const float smax = fmaxf(fmaxf(pmaxw[hw * 4], pmaxw[hw * 4 + 1]),
                               fmaxf(pmaxw[hw * 4 + 2], pmaxw[hw * 4 + 3]));
      #pragma unroll
      for (int ni = 0; ni < 2; ++ni) {
        int i = q * 32 + ni * 16 + l15;
        dvv[ni] = dbuf[hw * 128 + i];           // scaled d_i
        float tm = smax + dvv[ni];
        nml[ni] = -fmaxf(tm, 0.2f * tm);        // -ml (scaled, post-LR)
      }
      #pragma unroll
      for (int ks = 0; ks < 4; ++ks) {
        const int j0 = ks * 32 + lg * 8;
        float4 s03 = *(const float4*)(sbuf + hw * 128 + j0);
        float4 s47 = *(const float4*)(sbuf + hw * 128 + j0 + 4);
        float sj[8] = {s03.x, s03.y, s03.z, s03.w, s47.x, s47.y, s47.z, s47.w};
        short8 afr[4];
        #pragma unroll
        for (int mi = 0; mi < 4; ++mi)
          afr[mi] = *(const short8*)(smem + AB + ht_byte(hw * 64 + mi * 16 + l15, j0));
        short8 bfr[2];
        #pragma unroll
        for (int ni = 0; ni < 2; ++ni) {
          float e[8];
          #pragma unroll
          for (int jj = 0; jj < 8; ++jj) {
            float t = sj[jj] + dvv[ni];
            t = fmaxf(t, 0.2f * t);
            e[jj] = exp2f(t + nml[ni]);
          }
          den[ni] += ((e[0] + e[1]) + (e[2] + e[3])) + ((e[4] + e[5]) + (e[6] + e[7]));
          union { short8 s; unsigned int u[4]; } pk;
          #pragma unroll
          for (int t2 = 0; t2 < 4; ++t2) pk.u[t2] = pk2(e[2 * t2], e[2 * t2 + 1]);
          bfr[ni] = pk.s;
        }
        #pragma unroll
        for (int mi = 0; mi < 4; ++mi)
          #pragma unroll
          for (int ni = 0; ni < 2; ++ni)
            facc[mi][ni] = __builtin_amdgcn_mfma_f32_16x16x32_bf16(
                afr[mi], bfr[ni], facc[mi][ni], 0, 0, 0);
      }
      float rvv[2];
      #pragma unroll
      for (int ni = 0; ni < 2; ++ni) {
        float d2 = den[ni];
        d2 += __shfl_xor(d2, 16);
        d2 += __shfl_xor(d2, 32);
        rvv[ni] = 1.f / d2;
      }
      __syncthreads();                      // all Ht reads complete

      // ---- F-write: next Xs into AB (l<2) or final reduction (l==2) ----
      if (l < 2) {
        // D: row=feature c, col=node i. out = r_i*facc + bias -> next Xs.
        #pragma unroll
        for (int mi = 0; mi < 4; ++mi) {
          int c0 = hw * 64 + mi * 16 + lg * 4;
          float b0v = bsb[c0], b1v = bsb[c0 + 1], b2v = bsb[c0 + 2], b3v = bsb[c0 + 3];
          #pragma unroll
          for (int ni = 0; ni < 2; ++ni) {
            int i = q * 32 + ni * 16 + l15;
            float r = rvv[ni];
            uint2 u = { pk2(fmaf(facc[mi][ni][0], r, b0v), fmaf(facc[mi][ni][1], r, b1v)),
                        pk2(fmaf(facc[mi][ni][2], r, b2v), fmaf(facc[mi][ni][3], r, b3v)) };
            *(uint2*)(smem + AB + xs_byte(i, c0)) = u;
          }
        }
      } else {
        // final layer: sum over nodes i (ni-sum, shfl over l15, atomic over q)
        #pragma unroll
        for (int mi = 0; mi < 4; ++mi) {
          #pragma unroll
          for (int reg = 0; reg < 4; ++reg) {
            float pv2 = facc[mi][0][reg] * rvv[0] + facc[mi][1][reg] * rvv[1];
            pv2 += __shfl_xor(pv2, 1);
            pv2 += __shfl_xor(pv2, 2);
            pv2 += __shfl_xor(pv2, 4);
            pv2 += __shfl_xor(pv2, 8);
            if (l15 == 0)
              atomicAdd(&oac[hw * 64 + mi * 16 + lg * 4 + reg], pv2);
          }
        }
      }
    }
    __syncthreads();                        // next Xs / oac ready
  }

  // bias summed over 128 nodes = 128*b[c]
  if (tid < 256) out[(size_t)b * 256 + tid] = oac[tid] + 128.f * bsb[tid];
}

extern "C" void kernel_launch(void* const* d_in, const int* in_sizes, int n_in,
                              void* d_out, int out_size, void* d_ws, size_t ws_size,
                              hipStream_t stream) {
  const float* x   = (const float*)d_in[0];
  // d_in[1] = batch_mask (unused: uniform graph layout)
  const float* W0  = (const float*)d_in[2];
  const float* as0 = (const float*)d_in[3];
  const float* ad0 = (const float*)d_in[4];
  const float* b0  = (const float*)d_in[5];
  const float* W1  = (const float*)d_in[6];
  const float* as1 = (const float*)d_in[7];
  const float* ad1 = (const float*)d_in[8];
  const float* b1  = (const float*)d_in[9];
  const float* W2  = (const float*)d_in[10];
  const float* as2 = (const float*)d_in[11];
  const float* ad2 = (const float*)d_in[12];
  const float* b2  = (const float*)d_in[13];
  u16* wt = (u16*)d_ws;                      // 348,160 bytes used

  hipLaunchKernelGGL(prep_w, dim3(100), dim3(256), 0, stream,
                     W0, W1, W2, as0, ad0, as1, ad1, as2, ad2, wt);
  hipLaunchKernelGGL(gat_all, dim3(512), dim3(1024), 0, stream,
                     x, wt, b0, b1, b2, (float*)d_out);
}